// Round 1
// baseline (592.625 us; speedup 1.0000x reference)
//
#include <hip/hip_runtime.h>
#include <cmath>

namespace {
constexpr int NB = 16384;
constexpr int NS = 50;
constexpr int NK = 5;
constexpr int NH = 32;

__device__ __forceinline__ float wsum64(float v) {
#pragma unroll
  for (int off = 32; off; off >>= 1) v += __shfl_xor(v, off, 64);
  return v;
}

__device__ __forceinline__ float sigm(float x) { return 1.0f / (1.0f + expf(-x)); }

// ---------------- Kernel 1: embeddings, sim, top-5, x @ au_W1, au-BN stats ----
__global__ __launch_bounds__(256) void k1(
    const int* __restrict__ iid, const int* __restrict__ aid,
    const int* __restrict__ hist_iid, const int* __restrict__ hist_aid,
    const float* __restrict__ item_tab, const float* __restrict__ cate_tab,
    const float* __restrict__ au_W1, const float* __restrict__ au_b1,
    float* __restrict__ ws_y, int* __restrict__ ws_idx, float* __restrict__ ws_w,
    double* __restrict__ g_au_sum, double* __restrict__ g_au_sq)
{
  const int tid = threadIdx.x;
  const int lane = tid & 63;
  const int wv = tid >> 6;
  const int row = blockIdx.x * 4 + wv;

  __shared__ float w1sh[129 * 36];
  __shared__ float icsh[4][64];
  __shared__ float xsh[4][5][130];   // [k][0..63]=hist_w, [64]=cross, [65..128]=item_cat
  __shared__ float bsum[36], bsq[36];

  for (int i = tid; i < 129 * 36; i += 256) w1sh[i] = au_W1[i];
  if (tid < 36) { bsum[tid] = 0.f; bsq[tid] = 0.f; }

  const int iv = iid[row];
  const int cv = aid[row];
  const float ic = (lane < 32) ? item_tab[iv * NH + lane] : cate_tab[cv * NH + lane - 32];
  icsh[wv][lane] = ic;
  const float n1 = sqrtf(wsum64(ic * ic));
  __syncthreads();

  float dotv = 0.f, sim = -INFINITY;
  if (lane < NS) {
    const int hi = hist_iid[row * NS + lane];
    const int ha = hist_aid[row * NS + lane];
    const float4* ip = reinterpret_cast<const float4*>(item_tab + (size_t)hi * NH);
    const float4* cp = reinterpret_cast<const float4*>(cate_tab + (size_t)ha * NH);
    const float* ics = icsh[wv];
    float n2sq = 0.f;
#pragma unroll
    for (int q = 0; q < 8; q++) {
      float4 a = ip[q];
      dotv += ics[4*q+0]*a.x + ics[4*q+1]*a.y + ics[4*q+2]*a.z + ics[4*q+3]*a.w;
      n2sq += a.x*a.x + a.y*a.y + a.z*a.z + a.w*a.w;
    }
#pragma unroll
    for (int q = 0; q < 8; q++) {
      float4 a = cp[q];
      dotv += ics[32+4*q+0]*a.x + ics[32+4*q+1]*a.y + ics[32+4*q+2]*a.z + ics[32+4*q+3]*a.w;
      n2sq += a.x*a.x + a.y*a.y + a.z*a.z + a.w*a.w;
    }
    sim = dotv / fmaxf(n1 * sqrtf(n2sq), 1e-8f);
  }

  // top-5: descending value, ascending-index tie-break (matches jax.lax.top_k)
  float simw = sim;
  const int si = (lane < NS) ? lane : 1000;
  float vals[NK]; int idxs[NK];
#pragma unroll
  for (int r = 0; r < NK; r++) {
    float v = simw; int ii = si;
#pragma unroll
    for (int off = 32; off; off >>= 1) {
      float ov = __shfl_xor(v, off, 64);
      int   oi = __shfl_xor(ii, off, 64);
      if (ov > v || (ov == v && oi < ii)) { v = ov; ii = oi; }
    }
    vals[r] = v; idxs[r] = ii;
    if (si == ii) simw = -INFINITY;
  }

  const float ssum = vals[0] + vals[1] + vals[2] + vals[3] + vals[4] + 1e-8f;
  float wk[NK];
#pragma unroll
  for (int k = 0; k < NK; k++) wk[k] = vals[k] / ssum;

  float crossk[NK];
#pragma unroll
  for (int k = 0; k < NK; k++) crossk[k] = wk[k] * __shfl(dotv, idxs[k], 64);

#pragma unroll
  for (int k = 0; k < NK; k++) {
    const int hr = idxs[k];
    const int hi = hist_iid[row * NS + hr];
    const int ha = hist_aid[row * NS + hr];
    const float e = (lane < 32) ? item_tab[hi * NH + lane] : cate_tab[ha * NH + lane - 32];
    xsh[wv][k][lane] = wk[k] * e;
    xsh[wv][k][65 + lane] = ic;
  }
  if (lane == 0) {
#pragma unroll
    for (int k = 0; k < NK; k++) {
      xsh[wv][k][64] = crossk[k];
      ws_idx[row * NK + k] = idxs[k];
      ws_w[row * NK + k] = wk[k];
    }
  }
  __syncthreads();

#pragma unroll
  for (int t = 0; t < 3; t++) {
    const int id = lane + 64 * t;
    if (id < 180) {
      const int k = id / 36, j = id - 36 * k;
      float acc = au_b1[j];
      const float* xr = xsh[wv][k];
      for (int i = 0; i < 129; i++) acc = fmaf(xr[i], w1sh[i * 36 + j], acc);
      ws_y[(size_t)row * 180 + id] = acc;
      atomicAdd(&bsum[j], acc);
      atomicAdd(&bsq[j], acc * acc);
    }
  }
  __syncthreads();
  if (tid < 36) {
    atomicAdd(&g_au_sum[tid], (double)bsum[tid]);
    atomicAdd(&g_au_sq[tid],  (double)bsq[tid]);
  }
}

// ---------------- Kernel 3: dice3, au_out, final_hist, res @ l1_W, d1 stats ---
__global__ __launch_bounds__(256) void k3(
    const int* __restrict__ iid, const int* __restrict__ aid,
    const int* __restrict__ hist_iid, const int* __restrict__ hist_aid,
    const int* __restrict__ hist_rate,
    const float* __restrict__ item_tab, const float* __restrict__ cate_tab,
    const float* __restrict__ rate_tab,
    const float* __restrict__ au_alpha, const float* __restrict__ au_beta,
    const float* __restrict__ au_gamma, const float* __restrict__ au_bbeta,
    const float* __restrict__ au_W2, const float* __restrict__ au_b2,
    const float* __restrict__ l1_W, const float* __restrict__ l1_b,
    const float* __restrict__ ws_y, const int* __restrict__ ws_idx,
    const float* __restrict__ ws_w,
    const double* __restrict__ g_au_sum, const double* __restrict__ g_au_sq,
    float* __restrict__ ws_h1, double* __restrict__ g_d1_sum, double* __restrict__ g_d1_sq)
{
  const int tid = threadIdx.x, lane = tid & 63, wv = tid >> 6;
  const int row = blockIdx.x * 4 + wv;
  __shared__ float asc[36], bsc[36];
  __shared__ float res_sh[4][160];
  __shared__ float bsum[80], bsq[80];
  if (tid < 36) {
    const double m = g_au_sum[tid] * (1.0 / ((double)NB * NK));
    const double var = g_au_sq[tid] * (1.0 / ((double)NB * NK)) - m * m;
    const float rstd = (float)(1.0 / sqrt(var + 1e-8));
    const float g = au_gamma[tid] * rstd;
    asc[tid] = g; bsc[tid] = au_bbeta[tid] - (float)m * g;
  }
  if (tid < 80) { bsum[tid] = 0.f; bsq[tid] = 0.f; }
  __syncthreads();

  float aj = 0, bj = 0, betaj = 0, alphaj = 0, w2j = 0;
  if (lane < 36) {
    aj = asc[lane]; bj = bsc[lane];
    betaj = au_beta[lane]; alphaj = au_alpha[lane]; w2j = au_W2[lane];
  }
  const float bias2 = au_b2[0];
  float aout[NK];
#pragma unroll
  for (int k = 0; k < NK; k++) {
    float p = 0.f;
    if (lane < 36) {
      const float yv = ws_y[(size_t)row * 180 + k * 36 + lane];
      const float bn = yv * aj + bj;
      const float xn = sigm(betaj * bn);
      const float yd = alphaj * (1.f - xn) * yv + xn * yv;
      p = yd * w2j;
    }
    aout[k] = wsum64(p) + bias2;
  }

  int idxk[NK]; float wkk[NK];
#pragma unroll
  for (int k = 0; k < NK; k++) { idxk[k] = ws_idx[row * NK + k]; wkk[k] = ws_w[row * NK + k]; }

  const int iv = iid[row], cv = aid[row];
  const float ic = (lane < 32) ? item_tab[iv * NH + lane] : cate_tab[cv * NH + lane - 32];
  float fh0 = 0.f, fh1 = 0.f;
#pragma unroll
  for (int k = 0; k < NK; k++) {
    const int hr = idxk[k];
    const int hi = hist_iid[row * NS + hr], ha = hist_aid[row * NS + hr];
    const float e = (lane < 32) ? item_tab[hi * NH + lane] : cate_tab[ha * NH + lane - 32];
    fh0 += (wkk[k] * e) * aout[k];
    if (lane < 32) {
      const float tr = rate_tab[hist_rate[row * NS + hr] * NH + lane];
      fh1 += tr * aout[k];
    }
  }
  res_sh[wv][lane] = ic;
  res_sh[wv][64 + lane] = fh0;
  if (lane < 32) res_sh[wv][128 + lane] = fh1;
  __syncthreads();

#pragma unroll
  for (int t = 0; t < 2; t++) {
    const int o = lane + 64 * t;
    if (o < 80) {
      float acc = l1_b[o];
      const float* rs = res_sh[wv];
      for (int i = 0; i < 160; i++) acc = fmaf(rs[i], l1_W[i * 80 + o], acc);
      ws_h1[(size_t)row * 80 + o] = acc;
      atomicAdd(&bsum[o], acc);
      atomicAdd(&bsq[o], acc * acc);
    }
  }
  __syncthreads();
  if (tid < 80) {
    atomicAdd(&g_d1_sum[tid], (double)bsum[tid]);
    atomicAdd(&g_d1_sq[tid],  (double)bsq[tid]);
  }
}

// ---------------- Kernel 5: dice2(h1), h @ l2_W, d2 stats ---------------------
__global__ __launch_bounds__(256) void k5(
    const float* __restrict__ d1_alpha, const float* __restrict__ d1_beta,
    const float* __restrict__ d1_gamma, const float* __restrict__ d1_bbeta,
    const float* __restrict__ l2_W, const float* __restrict__ l2_b,
    const float* __restrict__ ws_h1,
    const double* __restrict__ g_d1_sum, const double* __restrict__ g_d1_sq,
    float* __restrict__ ws_h2, double* __restrict__ g_d2_sum, double* __restrict__ g_d2_sq)
{
  const int tid = threadIdx.x, lane = tid & 63, wv = tid >> 6;
  const int row = blockIdx.x * 4 + wv;
  __shared__ float a1[80], c1[80];
  __shared__ float hsh[4][80];
  __shared__ float bsum[40], bsq[40];
  if (tid < 80) {
    const double m = g_d1_sum[tid] * (1.0 / (double)NB);
    const double var = g_d1_sq[tid] * (1.0 / (double)NB) - m * m;
    const float rstd = (float)(1.0 / sqrt(var + 1e-8));
    const float g = d1_gamma[tid] * rstd;
    a1[tid] = g; c1[tid] = d1_bbeta[tid] - (float)m * g;
  }
  if (tid < 40) { bsum[tid] = 0.f; bsq[tid] = 0.f; }
  __syncthreads();
#pragma unroll
  for (int t = 0; t < 2; t++) {
    const int o = lane + 64 * t;
    if (o < 80) {
      const float v = ws_h1[(size_t)row * 80 + o];
      const float bn = v * a1[o] + c1[o];
      const float xn = sigm(d1_beta[o] * bn);
      hsh[wv][o] = d1_alpha[o] * (1.f - xn) * v + xn * v;
    }
  }
  __syncthreads();
  if (lane < 40) {
    float acc = l2_b[lane];
#pragma unroll
    for (int i = 0; i < 80; i++) acc = fmaf(hsh[wv][i], l2_W[i * 40 + lane], acc);
    ws_h2[(size_t)row * 40 + lane] = acc;
    atomicAdd(&bsum[lane], acc);
    atomicAdd(&bsq[lane], acc * acc);
  }
  __syncthreads();
  if (tid < 40) {
    atomicAdd(&g_d2_sum[tid], (double)bsum[tid]);
    atomicAdd(&g_d2_sq[tid],  (double)bsq[tid]);
  }
}

// ---------------- Kernel 7: dice2(h2), logits, probs, loss terms --------------
__global__ __launch_bounds__(256) void k7(
    const int* __restrict__ lb,
    const float* __restrict__ d2_alpha, const float* __restrict__ d2_beta,
    const float* __restrict__ d2_gamma, const float* __restrict__ d2_bbeta,
    const float* __restrict__ l3_W, const float* __restrict__ l3_b,
    const float* __restrict__ ws_h2,
    const double* __restrict__ g_d2_sum, const double* __restrict__ g_d2_sq,
    float* __restrict__ out, double* __restrict__ g_loss)
{
  const int tid = threadIdx.x, lane = tid & 63, wv = tid >> 6;
  const int row = blockIdx.x * 4 + wv;
  __shared__ float a2[40], c2[40];
  __shared__ float wls[4];
  if (tid < 40) {
    const double m = g_d2_sum[tid] * (1.0 / (double)NB);
    const double var = g_d2_sq[tid] * (1.0 / (double)NB) - m * m;
    const float rstd = (float)(1.0 / sqrt(var + 1e-8));
    const float g = d2_gamma[tid] * rstd;
    a2[tid] = g; c2[tid] = d2_bbeta[tid] - (float)m * g;
  }
  __syncthreads();
  float p = 0.f;
  if (lane < 40) {
    const float v = ws_h2[(size_t)row * 40 + lane];
    const float bn = v * a2[lane] + c2[lane];
    const float xn = sigm(d2_beta[lane] * bn);
    const float h = d2_alpha[lane] * (1.f - xn) * v + xn * v;
    p = h * l3_W[lane];
  }
  const float logit = wsum64(p) + l3_b[0];
  if (lane == 0) {
    out[row] = 1.f / (1.f + expf(-logit));
    const float lab = (float)lb[row];
    wls[wv] = fmaxf(logit, 0.f) - logit * lab + log1pf(expf(-fabsf(logit)));
  }
  __syncthreads();
  if (tid == 0) atomicAdd(g_loss, (double)(wls[0] + wls[1] + wls[2] + wls[3]));
}

__global__ void k8(const double* __restrict__ g_loss, float* __restrict__ out) {
  out[NB] = (float)(g_loss[0] * (1.0 / (double)NB));
}

} // namespace

extern "C" void kernel_launch(void* const* d_in, const int* in_sizes, int n_in,
                              void* d_out, int out_size, void* d_ws, size_t ws_size,
                              hipStream_t stream) {
  const int* iid       = (const int*)d_in[0];
  const int* aid       = (const int*)d_in[1];
  const int* lb        = (const int*)d_in[2];
  const int* hist_iid  = (const int*)d_in[3];
  const int* hist_aid  = (const int*)d_in[4];
  const int* hist_rate = (const int*)d_in[5];
  const float* item_tab = (const float*)d_in[6];
  const float* cate_tab = (const float*)d_in[7];
  const float* rate_tab = (const float*)d_in[8];
  const float* au_W1    = (const float*)d_in[9];
  const float* au_b1    = (const float*)d_in[10];
  const float* au_alpha = (const float*)d_in[11];
  const float* au_beta  = (const float*)d_in[12];
  const float* au_gamma = (const float*)d_in[13];
  const float* au_bbeta = (const float*)d_in[14];
  const float* au_W2    = (const float*)d_in[15];
  const float* au_b2    = (const float*)d_in[16];
  const float* l1_W     = (const float*)d_in[17];
  const float* l1_b     = (const float*)d_in[18];
  const float* d1_alpha = (const float*)d_in[19];
  const float* d1_beta  = (const float*)d_in[20];
  const float* d1_gamma = (const float*)d_in[21];
  const float* d1_bbeta = (const float*)d_in[22];
  const float* l2_W     = (const float*)d_in[23];
  const float* l2_b     = (const float*)d_in[24];
  const float* d2_alpha = (const float*)d_in[25];
  const float* d2_beta  = (const float*)d_in[26];
  const float* d2_gamma = (const float*)d_in[27];
  const float* d2_bbeta = (const float*)d_in[28];
  const float* l3_W     = (const float*)d_in[29];
  const float* l3_b     = (const float*)d_in[30];
  float* out = (float*)d_out;

  double* g = (double*)d_ws;
  double* g_au_sum = g;
  double* g_au_sq  = g + 36;
  double* g_d1_sum = g + 72;
  double* g_d1_sq  = g + 152;
  double* g_d2_sum = g + 232;
  double* g_d2_sq  = g + 272;
  double* g_loss   = g + 312;
  float* fbase  = (float*)((char*)d_ws + 4096);
  float* ws_y   = fbase;                       // NB*180
  float* ws_w   = fbase + (size_t)NB * 180;    // NB*5
  float* ws_h1  = fbase + (size_t)NB * 185;    // NB*80
  float* ws_h2  = fbase + (size_t)NB * 265;    // NB*40
  int*   ws_idx = (int*)(fbase + (size_t)NB * 305);  // NB*5

  hipMemsetAsync(d_ws, 0, 313 * sizeof(double), stream);
  dim3 blk(256), grd(NB / 4);
  k1<<<grd, blk, 0, stream>>>(iid, aid, hist_iid, hist_aid, item_tab, cate_tab,
                              au_W1, au_b1, ws_y, ws_idx, ws_w, g_au_sum, g_au_sq);
  k3<<<grd, blk, 0, stream>>>(iid, aid, hist_iid, hist_aid, hist_rate,
                              item_tab, cate_tab, rate_tab,
                              au_alpha, au_beta, au_gamma, au_bbeta, au_W2, au_b2,
                              l1_W, l1_b, ws_y, ws_idx, ws_w, g_au_sum, g_au_sq,
                              ws_h1, g_d1_sum, g_d1_sq);
  k5<<<grd, blk, 0, stream>>>(d1_alpha, d1_beta, d1_gamma, d1_bbeta, l2_W, l2_b,
                              ws_h1, g_d1_sum, g_d1_sq, ws_h2, g_d2_sum, g_d2_sq);
  k7<<<grd, blk, 0, stream>>>(lb, d2_alpha, d2_beta, d2_gamma, d2_bbeta, l3_W, l3_b,
                              ws_h2, g_d2_sum, g_d2_sq, out, g_loss);
  k8<<<1, 1, 0, stream>>>(g_loss, out);
}

// Round 2
// 207.549 us; speedup vs baseline: 2.8553x; 2.8553x over previous
//
#include <hip/hip_runtime.h>
#include <cmath>

namespace {
constexpr int NB = 16384;
constexpr int NS = 50;
constexpr int NK = 5;
constexpr int NH = 32;

__device__ __forceinline__ float wsum64(float v) {
#pragma unroll
  for (int off = 32; off; off >>= 1) v += __shfl_xor(v, off, 64);
  return v;
}

__device__ __forceinline__ float sigm(float x) { return 1.0f / (1.0f + expf(-x)); }

// ---- Kernel 1: embeddings, sim, top-5, x @ au_W1 (129x36), au-BN stats ------
// 256 thr = 4 waves, each wave owns 1 row per iteration, 4 iterations/block.
__global__ __launch_bounds__(256) void k1(
    const int* __restrict__ iid, const int* __restrict__ aid,
    const int* __restrict__ hist_iid, const int* __restrict__ hist_aid,
    const int* __restrict__ hist_rate,
    const float* __restrict__ item_tab, const float* __restrict__ cate_tab,
    const float* __restrict__ au_W1, const float* __restrict__ au_b1,
    float* __restrict__ ws_y, float* __restrict__ ws_w,
    int* __restrict__ ws_hi, int* __restrict__ ws_ha, int* __restrict__ ws_hr,
    double* __restrict__ g_au_sum, double* __restrict__ g_au_sq)
{
  const int tid = threadIdx.x;
  const int lane = tid & 63;
  const int wv = tid >> 6;

  __shared__ float w1t[36][132];     // transposed au_W1: [j][i], i<129
  __shared__ float xsh[4][5][132];   // per-wave x rows: [0..63]=hist_w,[64]=cross,[65..128]=ic
  __shared__ float icsh[4][64];
  __shared__ float psum[184], psq[184];

  for (int e = tid; e < 129 * 36; e += 256) {
    const int i = e / 36, j = e - 36 * i;
    w1t[j][i] = au_W1[e];
  }
  if (tid < 180) { psum[tid] = 0.f; psq[tid] = 0.f; }
  __syncthreads();

  // per-slot register stat accumulators (slot t -> fixed (j,k) across row iters)
  float ssum[3] = {0.f, 0.f, 0.f}, ssq[3] = {0.f, 0.f, 0.f};

  for (int r = 0; r < 4; r++) {
    const int row = blockIdx.x * 16 + r * 4 + wv;

    const int iv = iid[row];
    const int cv = aid[row];
    const float ic = (lane < 32) ? item_tab[iv * NH + lane] : cate_tab[cv * NH + lane - 32];
    icsh[wv][lane] = ic;
    const float n1 = sqrtf(wsum64(ic * ic));

    int hi = 0, ha = 0, rv = 0;
    float dotv = 0.f, sim = -INFINITY;
    if (lane < NS) {
      hi = hist_iid[row * NS + lane];
      ha = hist_aid[row * NS + lane];
      rv = hist_rate[row * NS + lane];
      const float4* ip = reinterpret_cast<const float4*>(item_tab + (size_t)hi * NH);
      const float4* cp = reinterpret_cast<const float4*>(cate_tab + (size_t)ha * NH);
      const float* ics = icsh[wv];
      float n2sq = 0.f;
#pragma unroll
      for (int q = 0; q < 8; q++) {
        float4 a = ip[q];
        dotv += ics[4*q+0]*a.x + ics[4*q+1]*a.y + ics[4*q+2]*a.z + ics[4*q+3]*a.w;
        n2sq += a.x*a.x + a.y*a.y + a.z*a.z + a.w*a.w;
      }
#pragma unroll
      for (int q = 0; q < 8; q++) {
        float4 a = cp[q];
        dotv += ics[32+4*q+0]*a.x + ics[32+4*q+1]*a.y + ics[32+4*q+2]*a.z + ics[32+4*q+3]*a.w;
        n2sq += a.x*a.x + a.y*a.y + a.z*a.z + a.w*a.w;
      }
      sim = dotv / fmaxf(n1 * sqrtf(n2sq), 1e-8f);
    }

    // top-5: descending value, ascending-index tie-break
    float simw = sim;
    const int si = (lane < NS) ? lane : 1000;
    float vals[NK]; int idxs[NK];
#pragma unroll
    for (int rr = 0; rr < NK; rr++) {
      float v = simw; int ii = si;
#pragma unroll
      for (int off = 32; off; off >>= 1) {
        float ov = __shfl_xor(v, off, 64);
        int   oi = __shfl_xor(ii, off, 64);
        if (ov > v || (ov == v && oi < ii)) { v = ov; ii = oi; }
      }
      vals[rr] = v; idxs[rr] = ii;
      if (si == ii) simw = -INFINITY;
    }

    const float ssumw = vals[0] + vals[1] + vals[2] + vals[3] + vals[4] + 1e-8f;
#pragma unroll
    for (int k = 0; k < NK; k++) {
      const float wk = vals[k] / ssumw;
      const float crossk = wk * __shfl(dotv, idxs[k], 64);
      const int hik = __shfl(hi, idxs[k], 64);
      const int hak = __shfl(ha, idxs[k], 64);
      const int rvk = __shfl(rv, idxs[k], 64);
      const float e = (lane < 32) ? item_tab[hik * NH + lane] : cate_tab[hak * NH + lane - 32];
      xsh[wv][k][lane] = wk * e;
      xsh[wv][k][65 + lane] = ic;
      if (lane == 0) xsh[wv][k][64] = crossk;
      if (lane == k) {
        ws_w[row * NK + k] = wk;
        ws_hi[row * NK + k] = hik;
        ws_ha[row * NK + k] = hak;
        ws_hr[row * NK + k] = rvk;
      }
    }

    // GEMM: wave computes its row's 180 outputs; id64 -> j=id/5 (broadcast W), k=id%5
#pragma unroll
    for (int t = 0; t < 3; t++) {
      const int id64 = lane + 64 * t;
      if (id64 < 180) {
        const int j = id64 / 5, k = id64 - 5 * j;
        float acc = au_b1[j];
        const float4* wr = reinterpret_cast<const float4*>(&w1t[j][0]);
        const float4* xr = reinterpret_cast<const float4*>(&xsh[wv][k][0]);
#pragma unroll 8
        for (int q = 0; q < 32; q++) {
          const float4 a = wr[q];
          const float4 b = xr[q];
          acc = fmaf(a.x, b.x, acc); acc = fmaf(a.y, b.y, acc);
          acc = fmaf(a.z, b.z, acc); acc = fmaf(a.w, b.w, acc);
        }
        acc = fmaf(w1t[j][128], xsh[wv][k][128], acc);
        ws_y[(size_t)row * 180 + k * 36 + j] = acc;
        ssum[t] += acc; ssq[t] += acc * acc;
      }
    }
  }

  // flush stats: reg -> LDS (4-way atomic) -> fold over k -> global
#pragma unroll
  for (int t = 0; t < 3; t++) {
    const int id64 = lane + 64 * t;
    if (id64 < 180) {
      atomicAdd(&psum[id64], ssum[t]);
      atomicAdd(&psq[id64], ssq[t]);
    }
  }
  __syncthreads();
  if (tid < 36) {
    float s = 0.f, q = 0.f;
#pragma unroll
    for (int k = 0; k < NK; k++) { s += psum[tid * 5 + k]; q += psq[tid * 5 + k]; }
    atomicAdd(&g_au_sum[tid], (double)s);
    atomicAdd(&g_au_sq[tid], (double)q);
  }
}

// ---- Kernel 3: dice3, au_out, final_hist, res @ l1_W (160x80), d1 stats -----
// 512 thr = 8 waves, 2 row iterations/block.
__global__ __launch_bounds__(512) void k3(
    const int* __restrict__ iid, const int* __restrict__ aid,
    const float* __restrict__ item_tab, const float* __restrict__ cate_tab,
    const float* __restrict__ rate_tab,
    const float* __restrict__ au_alpha, const float* __restrict__ au_beta,
    const float* __restrict__ au_gamma, const float* __restrict__ au_bbeta,
    const float* __restrict__ au_W2, const float* __restrict__ au_b2,
    const float* __restrict__ l1_W, const float* __restrict__ l1_b,
    const float* __restrict__ ws_y, const float* __restrict__ ws_w,
    const int* __restrict__ ws_hi, const int* __restrict__ ws_ha,
    const int* __restrict__ ws_hr,
    const double* __restrict__ g_au_sum, const double* __restrict__ g_au_sq,
    float* __restrict__ ws_h1, double* __restrict__ g_d1_sum, double* __restrict__ g_d1_sq)
{
  const int tid = threadIdx.x, lane = tid & 63, wv = tid >> 6;
  __shared__ float l1t[80][164];     // transposed l1_W: [o][i], i<160
  __shared__ float res_sh[8][164];
  __shared__ float asc[36], bsc[36];
  __shared__ float psum[80], psq[80];

  for (int e = tid; e < 160 * 80; e += 512) {
    const int i = e / 80, o = e - 80 * i;
    l1t[o][i] = l1_W[e];
  }
  if (tid < 36) {
    const double m = g_au_sum[tid] * (1.0 / ((double)NB * NK));
    const double var = g_au_sq[tid] * (1.0 / ((double)NB * NK)) - m * m;
    const float rstd = (float)(1.0 / sqrt(var + 1e-8));
    const float g = au_gamma[tid] * rstd;
    asc[tid] = g; bsc[tid] = au_bbeta[tid] - (float)m * g;
  }
  if (tid < 80) { psum[tid] = 0.f; psq[tid] = 0.f; }
  __syncthreads();

  float aj = 0, bj = 0, betaj = 0, alphaj = 0, w2j = 0;
  if (lane < 36) {
    aj = asc[lane]; bj = bsc[lane];
    betaj = au_beta[lane]; alphaj = au_alpha[lane]; w2j = au_W2[lane];
  }
  const float bias2 = au_b2[0];

  float ssum[2] = {0.f, 0.f}, ssq[2] = {0.f, 0.f};

  for (int r = 0; r < 2; r++) {
    const int row = blockIdx.x * 16 + r * 8 + wv;

    float aout[NK];
#pragma unroll
    for (int k = 0; k < NK; k++) {
      float p = 0.f;
      if (lane < 36) {
        const float yv = ws_y[(size_t)row * 180 + k * 36 + lane];
        const float bn = yv * aj + bj;
        const float xn = sigm(betaj * bn);
        p = (alphaj * (1.f - xn) * yv + xn * yv) * w2j;
      }
      aout[k] = wsum64(p) + bias2;
    }

    const int iv = iid[row], cv = aid[row];
    const float ic = (lane < 32) ? item_tab[iv * NH + lane] : cate_tab[cv * NH + lane - 32];
    float fh0 = 0.f, fh1 = 0.f;
#pragma unroll
    for (int k = 0; k < NK; k++) {
      const int hik = ws_hi[row * NK + k];
      const int hak = ws_ha[row * NK + k];
      const int rvk = ws_hr[row * NK + k];
      const float wk = ws_w[row * NK + k];
      const float e = (lane < 32) ? item_tab[hik * NH + lane] : cate_tab[hak * NH + lane - 32];
      fh0 = fmaf(wk * e, aout[k], fh0);
      if (lane < 32) fh1 = fmaf(rate_tab[rvk * NH + lane], aout[k], fh1);
    }
    res_sh[wv][lane] = ic;
    res_sh[wv][64 + lane] = fh0;
    if (lane < 32) res_sh[wv][128 + lane] = fh1;

#pragma unroll
    for (int t = 0; t < 2; t++) {
      const int o = lane + 64 * t;
      if (o < 80) {
        float acc = l1_b[o];
        const float4* wr = reinterpret_cast<const float4*>(&l1t[o][0]);
        const float4* xr = reinterpret_cast<const float4*>(&res_sh[wv][0]);
#pragma unroll 8
        for (int q = 0; q < 40; q++) {
          const float4 a = wr[q];
          const float4 b = xr[q];
          acc = fmaf(a.x, b.x, acc); acc = fmaf(a.y, b.y, acc);
          acc = fmaf(a.z, b.z, acc); acc = fmaf(a.w, b.w, acc);
        }
        ws_h1[(size_t)row * 80 + o] = acc;
        ssum[t] += acc; ssq[t] += acc * acc;
      }
    }
  }

#pragma unroll
  for (int t = 0; t < 2; t++) {
    const int o = lane + 64 * t;
    if (o < 80) { atomicAdd(&psum[o], ssum[t]); atomicAdd(&psq[o], ssq[t]); }
  }
  __syncthreads();
  if (tid < 80) {
    atomicAdd(&g_d1_sum[tid], (double)psum[tid]);
    atomicAdd(&g_d1_sq[tid], (double)psq[tid]);
  }
}

// ---- Kernel 5: dice2(h1), h @ l2_W (80x40), d2 stats ------------------------
__global__ __launch_bounds__(256) void k5(
    const float* __restrict__ d1_alpha, const float* __restrict__ d1_beta,
    const float* __restrict__ d1_gamma, const float* __restrict__ d1_bbeta,
    const float* __restrict__ l2_W, const float* __restrict__ l2_b,
    const float* __restrict__ ws_h1,
    const double* __restrict__ g_d1_sum, const double* __restrict__ g_d1_sq,
    float* __restrict__ ws_h2, double* __restrict__ g_d2_sum, double* __restrict__ g_d2_sq)
{
  const int tid = threadIdx.x, lane = tid & 63, wv = tid >> 6;
  __shared__ float l2t[40][84];     // transposed l2_W: [o][i], i<80
  __shared__ float hsh[4][84];
  __shared__ float a1[80], c1[80];
  __shared__ float psum[40], psq[40];

  for (int e = tid; e < 80 * 40; e += 256) {
    const int i = e / 40, o = e - 40 * i;
    l2t[o][i] = l2_W[e];
  }
  if (tid < 80) {
    const double m = g_d1_sum[tid] * (1.0 / (double)NB);
    const double var = g_d1_sq[tid] * (1.0 / (double)NB) - m * m;
    const float rstd = (float)(1.0 / sqrt(var + 1e-8));
    const float g = d1_gamma[tid] * rstd;
    a1[tid] = g; c1[tid] = d1_bbeta[tid] - (float)m * g;
  }
  if (tid < 40) { psum[tid] = 0.f; psq[tid] = 0.f; }
  __syncthreads();

  float ssum = 0.f, ssq = 0.f;
  for (int r = 0; r < 4; r++) {
    const int row = blockIdx.x * 16 + r * 4 + wv;
#pragma unroll
    for (int t = 0; t < 2; t++) {
      const int o = lane + 64 * t;
      if (o < 80) {
        const float v = ws_h1[(size_t)row * 80 + o];
        const float bn = v * a1[o] + c1[o];
        const float xn = sigm(d1_beta[o] * bn);
        hsh[wv][o] = d1_alpha[o] * (1.f - xn) * v + xn * v;
      }
    }
    if (lane < 40) {
      float acc = l2_b[lane];
      const float4* wr = reinterpret_cast<const float4*>(&l2t[lane][0]);
      const float4* xr = reinterpret_cast<const float4*>(&hsh[wv][0]);
#pragma unroll 5
      for (int q = 0; q < 20; q++) {
        const float4 a = wr[q];
        const float4 b = xr[q];
        acc = fmaf(a.x, b.x, acc); acc = fmaf(a.y, b.y, acc);
        acc = fmaf(a.z, b.z, acc); acc = fmaf(a.w, b.w, acc);
      }
      ws_h2[(size_t)row * 40 + lane] = acc;
      ssum += acc; ssq += acc * acc;
    }
  }
  if (lane < 40) { atomicAdd(&psum[lane], ssum); atomicAdd(&psq[lane], ssq); }
  __syncthreads();
  if (tid < 40) {
    atomicAdd(&g_d2_sum[tid], (double)psum[tid]);
    atomicAdd(&g_d2_sq[tid], (double)psq[tid]);
  }
}

// ---- Kernel 7: dice2(h2), logits, probs, loss -------------------------------
__global__ __launch_bounds__(256) void k7(
    const int* __restrict__ lb,
    const float* __restrict__ d2_alpha, const float* __restrict__ d2_beta,
    const float* __restrict__ d2_gamma, const float* __restrict__ d2_bbeta,
    const float* __restrict__ l3_W, const float* __restrict__ l3_b,
    const float* __restrict__ ws_h2,
    const double* __restrict__ g_d2_sum, const double* __restrict__ g_d2_sq,
    float* __restrict__ out, double* __restrict__ g_loss)
{
  const int tid = threadIdx.x, lane = tid & 63, wv = tid >> 6;
  __shared__ float a2[40], c2[40];
  __shared__ float wls[4];
  if (tid < 40) {
    const double m = g_d2_sum[tid] * (1.0 / (double)NB);
    const double var = g_d2_sq[tid] * (1.0 / (double)NB) - m * m;
    const float rstd = (float)(1.0 / sqrt(var + 1e-8));
    const float g = d2_gamma[tid] * rstd;
    a2[tid] = g; c2[tid] = d2_bbeta[tid] - (float)m * g;
  }
  __syncthreads();

  float wj = 0, b2j = 0, c2j = 0, betaj = 0, alphaj = 0;
  if (lane < 40) {
    wj = l3_W[lane]; b2j = a2[lane]; c2j = c2[lane];
    betaj = d2_beta[lane]; alphaj = d2_alpha[lane];
  }
  const float b3 = l3_b[0];

  float lacc = 0.f;
  for (int r = 0; r < 4; r++) {
    const int row = blockIdx.x * 16 + r * 4 + wv;
    float p = 0.f;
    if (lane < 40) {
      const float v = ws_h2[(size_t)row * 40 + lane];
      const float bn = v * b2j + c2j;
      const float xn = sigm(betaj * bn);
      p = (alphaj * (1.f - xn) * v + xn * v) * wj;
    }
    const float logit = wsum64(p) + b3;
    if (lane == 0) {
      out[row] = 1.f / (1.f + expf(-logit));
      const float lab = (float)lb[row];
      lacc += fmaxf(logit, 0.f) - logit * lab + log1pf(expf(-fabsf(logit)));
    }
  }
  if (lane == 0) wls[wv] = lacc;
  __syncthreads();
  if (tid == 0) atomicAdd(g_loss, (double)(wls[0] + wls[1] + wls[2] + wls[3]));
}

__global__ void k8(const double* __restrict__ g_loss, float* __restrict__ out) {
  out[NB] = (float)(g_loss[0] * (1.0 / (double)NB));
}

} // namespace

extern "C" void kernel_launch(void* const* d_in, const int* in_sizes, int n_in,
                              void* d_out, int out_size, void* d_ws, size_t ws_size,
                              hipStream_t stream) {
  const int* iid       = (const int*)d_in[0];
  const int* aid       = (const int*)d_in[1];
  const int* lb        = (const int*)d_in[2];
  const int* hist_iid  = (const int*)d_in[3];
  const int* hist_aid  = (const int*)d_in[4];
  const int* hist_rate = (const int*)d_in[5];
  const float* item_tab = (const float*)d_in[6];
  const float* cate_tab = (const float*)d_in[7];
  const float* rate_tab = (const float*)d_in[8];
  const float* au_W1    = (const float*)d_in[9];
  const float* au_b1    = (const float*)d_in[10];
  const float* au_alpha = (const float*)d_in[11];
  const float* au_beta  = (const float*)d_in[12];
  const float* au_gamma = (const float*)d_in[13];
  const float* au_bbeta = (const float*)d_in[14];
  const float* au_W2    = (const float*)d_in[15];
  const float* au_b2    = (const float*)d_in[16];
  const float* l1_W     = (const float*)d_in[17];
  const float* l1_b     = (const float*)d_in[18];
  const float* d1_alpha = (const float*)d_in[19];
  const float* d1_beta  = (const float*)d_in[20];
  const float* d1_gamma = (const float*)d_in[21];
  const float* d1_bbeta = (const float*)d_in[22];
  const float* l2_W     = (const float*)d_in[23];
  const float* l2_b     = (const float*)d_in[24];
  const float* d2_alpha = (const float*)d_in[25];
  const float* d2_beta  = (const float*)d_in[26];
  const float* d2_gamma = (const float*)d_in[27];
  const float* d2_bbeta = (const float*)d_in[28];
  const float* l3_W     = (const float*)d_in[29];
  const float* l3_b     = (const float*)d_in[30];
  float* out = (float*)d_out;

  double* g = (double*)d_ws;
  double* g_au_sum = g;
  double* g_au_sq  = g + 36;
  double* g_d1_sum = g + 72;
  double* g_d1_sq  = g + 152;
  double* g_d2_sum = g + 232;
  double* g_d2_sq  = g + 272;
  double* g_loss   = g + 312;
  float* fbase  = (float*)((char*)d_ws + 4096);
  float* ws_y   = fbase;                       // NB*180
  float* ws_w   = fbase + (size_t)NB * 180;    // NB*5
  float* ws_h1  = fbase + (size_t)NB * 185;    // NB*80
  float* ws_h2  = fbase + (size_t)NB * 265;    // NB*40
  int*   ws_hi  = (int*)(fbase + (size_t)NB * 305);  // NB*5
  int*   ws_ha  = ws_hi + (size_t)NB * NK;
  int*   ws_hr  = ws_ha + (size_t)NB * NK;

  hipMemsetAsync(d_ws, 0, 313 * sizeof(double), stream);
  dim3 grd(NB / 16);
  k1<<<grd, 256, 0, stream>>>(iid, aid, hist_iid, hist_aid, hist_rate,
                              item_tab, cate_tab, au_W1, au_b1,
                              ws_y, ws_w, ws_hi, ws_ha, ws_hr, g_au_sum, g_au_sq);
  k3<<<grd, 512, 0, stream>>>(iid, aid, item_tab, cate_tab, rate_tab,
                              au_alpha, au_beta, au_gamma, au_bbeta, au_W2, au_b2,
                              l1_W, l1_b, ws_y, ws_w, ws_hi, ws_ha, ws_hr,
                              g_au_sum, g_au_sq, ws_h1, g_d1_sum, g_d1_sq);
  k5<<<grd, 256, 0, stream>>>(d1_alpha, d1_beta, d1_gamma, d1_bbeta, l2_W, l2_b,
                              ws_h1, g_d1_sum, g_d1_sq, ws_h2, g_d2_sum, g_d2_sq);
  k7<<<grd, 256, 0, stream>>>(lb, d2_alpha, d2_beta, d2_gamma, d2_bbeta, l3_W, l3_b,
                              ws_h2, g_d2_sum, g_d2_sq, out, g_loss);
  k8<<<1, 1, 0, stream>>>(g_loss, out);
}